// Round 1
// baseline (7944.795 us; speedup 1.0000x reference)
//
#include <hip/hip_runtime.h>
#include <math.h>

// Problem constants
#define TT   64
#define BB   2048
#define OBSN 128
#define CTRLN 16
#define LATN 128
#define NMN  16
#define HDN  128

__device__ __forceinline__ float sigf(float x) { return 1.0f / (1.0f + expf(-x)); }

// ---------------------------------------------------------------------------
// Build Wmix (272 x 2048): rows 0..127 <- A[i,j,k] (z), 128..143 <- Bm (u),
// 144..271 <- C (w). Column c = i*128 + j.
// ---------------------------------------------------------------------------
__global__ __launch_bounds__(256) void prep_wmix_k(
    const float* __restrict__ Aw, const float* __restrict__ Bw,
    const float* __restrict__ Cw, float* __restrict__ Wmix)
{
    int idx = blockIdx.x * 256 + threadIdx.x;
    if (idx >= 272 * 2048) return;
    int k = idx >> 11;
    int c = idx & 2047;
    int i = c >> 7, j = c & 127;
    float v;
    if (k < 128)      v = Aw[(i * 128 + j) * 128 + k];
    else if (k < 144) v = Bw[(i * 128 + j) * 16 + (k - 128)];
    else              v = Cw[(i * 128 + j) * 128 + (k - 144)];
    Wmix[idx] = v;
}

// ---------------------------------------------------------------------------
// One LSTM step: gates = [x_t | h_in] @ [Wx;Wh] + b, then c/h update.
// Block: 32 rows x 32 h-cols (x 4 gates). Grid (64,4). h double-buffered.
// ---------------------------------------------------------------------------
__global__ __launch_bounds__(256) void lstm_step_k(
    const float* __restrict__ xt, const float* __restrict__ hin,
    float* __restrict__ hout, float* __restrict__ cst,
    const float* __restrict__ Wx, const float* __restrict__ Wh,
    const float* __restrict__ bias, int first)
{
    __shared__ float As[16][36];    // [kk][r]
    __shared__ float Ws[16][128];   // [kk][g*32+jj]
    const int tid = threadIdx.x;
    const int row0 = blockIdx.x * 32;
    const int hc0  = blockIdx.y * 32;
    const int tjj = tid & 31;
    const int trg = tid >> 5;       // 0..7 -> rows trg*4..trg*4+3
    float acc[4][4];
#pragma unroll
    for (int a = 0; a < 4; a++)
#pragma unroll
        for (int b = 0; b < 4; b++) acc[a][b] = 0.f;

    for (int kc = 0; kc < 256; kc += 16) {
        __syncthreads();
#pragma unroll
        for (int e = 0; e < 2; e++) {
            int idx = tid + e * 256;
            int r = idx >> 4, kk = idx & 15;
            int k = kc + kk;
            float v;
            if (k < 128) v = xt[(row0 + r) * 128 + k];
            else         v = first ? 0.f : hin[(row0 + r) * 128 + (k - 128)];
            As[kk][r] = v;
        }
#pragma unroll
        for (int e = 0; e < 8; e++) {
            int idx = tid + e * 256;
            int kk = idx >> 7, cc = idx & 127;
            int g = cc >> 5, jj = cc & 31;
            int k = kc + kk;
            const float* Wrow = (k < 128) ? (Wx + k * 512) : (Wh + (k - 128) * 512);
            Ws[kk][cc] = Wrow[g * 128 + hc0 + jj];
        }
        __syncthreads();
#pragma unroll
        for (int kk = 0; kk < 16; kk++) {
            const float4 a4 = *(const float4*)&As[kk][trg * 4];
            const float w0 = Ws[kk][tjj];
            const float w1 = Ws[kk][32 + tjj];
            const float w2 = Ws[kk][64 + tjj];
            const float w3 = Ws[kk][96 + tjj];
            const float av[4] = {a4.x, a4.y, a4.z, a4.w};
#pragma unroll
            for (int rr = 0; rr < 4; rr++) {
                acc[rr][0] += av[rr] * w0;
                acc[rr][1] += av[rr] * w1;
                acc[rr][2] += av[rr] * w2;
                acc[rr][3] += av[rr] * w3;
            }
        }
    }
    const int j = hc0 + tjj;
#pragma unroll
    for (int rr = 0; rr < 4; rr++) {
        const int r = row0 + trg * 4 + rr;
        float gi = acc[rr][0] + bias[j];
        float gf = acc[rr][1] + bias[128 + j];
        float gg = acc[rr][2] + bias[256 + j];
        float go = acc[rr][3] + bias[384 + j];
        float cold = first ? 0.f : cst[r * 128 + j];
        float cn = sigf(gf) * cold + sigf(gi) * tanhf(gg);
        float hn = sigf(go) * tanhf(cn);
        cst[r * 128 + j] = cn;
        hout[r * 128 + j] = hn;
    }
}

// ---------------------------------------------------------------------------
// Generic C = act(A@W + b). 64x64 tile, 4x4 micro. Used for small dense layers.
// ---------------------------------------------------------------------------
template <int RELU>
__global__ __launch_bounds__(256) void gemm_bias_k(
    const float* __restrict__ A, const float* __restrict__ W,
    const float* __restrict__ bias, float* __restrict__ Cout,
    int M, int K, int N)
{
    __shared__ float As[16][68];
    __shared__ float Ws[16][64];
    const int tid = threadIdx.x;
    const int row0 = blockIdx.x * 64;
    const int col0 = blockIdx.y * 64;
    const int tx = tid & 15, ty = tid >> 4;
    float acc[4][4];
#pragma unroll
    for (int a = 0; a < 4; a++)
#pragma unroll
        for (int b = 0; b < 4; b++) acc[a][b] = 0.f;

    for (int kc = 0; kc < K; kc += 16) {
        __syncthreads();
#pragma unroll
        for (int e = 0; e < 4; e++) {
            int idx = tid + e * 256;
            int r = idx >> 4, kk = idx & 15;
            As[kk][r] = A[(size_t)(row0 + r) * K + kc + kk];
        }
#pragma unroll
        for (int e = 0; e < 4; e++) {
            int idx = tid + e * 256;
            int kk = idx >> 6, jj = idx & 63;
            Ws[kk][jj] = W[(kc + kk) * N + col0 + jj];
        }
        __syncthreads();
#pragma unroll
        for (int kk = 0; kk < 16; kk++) {
            const float4 a4 = *(const float4*)&As[kk][ty * 4];
            const float4 w4 = *(const float4*)&Ws[kk][tx * 4];
            const float av[4] = {a4.x, a4.y, a4.z, a4.w};
            const float wv[4] = {w4.x, w4.y, w4.z, w4.w};
#pragma unroll
            for (int r = 0; r < 4; r++)
#pragma unroll
                for (int j = 0; j < 4; j++) acc[r][j] += av[r] * wv[j];
        }
    }
#pragma unroll
    for (int r = 0; r < 4; r++)
#pragma unroll
        for (int j = 0; j < 4; j++) {
            int gr = row0 + ty * 4 + r, gc = col0 + tx * 4 + j;
            float v = acc[r][j] + bias[gc];
            if (RELU) v = fmaxf(v, 0.f);
            Cout[(size_t)gr * N + gc] = v;
        }
}

// ---------------------------------------------------------------------------
// out[b,j] = (A@W)[b,j] + b[j] + exp(((A@W)[b,j+128] + b[j+128])/2) * eps[b,j]
// A:(M,128) W:(128,256). Block: 32 rows x 64 j's (both halves). Grid (M/32, 2).
// ---------------------------------------------------------------------------
__global__ __launch_bounds__(256) void gemm_meanvar_k(
    const float* __restrict__ A, const float* __restrict__ W,
    const float* __restrict__ bias, const float* __restrict__ eps,
    float* __restrict__ out)
{
    __shared__ float As[16][36];
    __shared__ float Ws[16][128];   // [kk][half*64 + jj]
    const int tid = threadIdx.x;
    const int row0 = blockIdx.x * 32;
    const int j0 = blockIdx.y * 64;
    const int tjx = tid & 31;       // j pair base = 2*tjx
    const int trg = tid >> 5;
    float am[4][2], al[4][2];
#pragma unroll
    for (int a = 0; a < 4; a++) { am[a][0] = am[a][1] = 0.f; al[a][0] = al[a][1] = 0.f; }

    for (int kc = 0; kc < 128; kc += 16) {
        __syncthreads();
#pragma unroll
        for (int e = 0; e < 2; e++) {
            int idx = tid + e * 256;
            int r = idx >> 4, kk = idx & 15;
            As[kk][r] = A[(row0 + r) * 128 + kc + kk];
        }
#pragma unroll
        for (int e = 0; e < 2; e++) {
            int idx = tid + e * 256;      // 512 float4s
            int lin = idx * 4;
            int kk = lin >> 7, cc = lin & 127;
            int half = cc >> 6, jj = cc & 63;
            *(float4*)&Ws[kk][half * 64 + jj] =
                *(const float4*)(W + (kc + kk) * 256 + half * 128 + j0 + jj);
        }
        __syncthreads();
#pragma unroll
        for (int kk = 0; kk < 16; kk++) {
            const float4 a4 = *(const float4*)&As[kk][trg * 4];
            const float2 wm = *(const float2*)&Ws[kk][2 * tjx];
            const float2 wl = *(const float2*)&Ws[kk][64 + 2 * tjx];
            const float av[4] = {a4.x, a4.y, a4.z, a4.w};
#pragma unroll
            for (int rr = 0; rr < 4; rr++) {
                am[rr][0] += av[rr] * wm.x; am[rr][1] += av[rr] * wm.y;
                al[rr][0] += av[rr] * wl.x; al[rr][1] += av[rr] * wl.y;
            }
        }
    }
#pragma unroll
    for (int rr = 0; rr < 4; rr++)
#pragma unroll
        for (int jj = 0; jj < 2; jj++) {
            int r = row0 + trg * 4 + rr;
            int j = j0 + 2 * tjx + jj;
            float m = am[rr][jj] + bias[j];
            float l = al[rr][jj] + bias[128 + j];
            out[r * 128 + j] = m + expf(0.5f * l) * eps[r * 128 + j];
        }
}

// ---------------------------------------------------------------------------
// r = relu([z|x|u] @ rec_W1 + b1). K=272, N=128. Block 32x64. Grid (64,2).
// ---------------------------------------------------------------------------
__global__ __launch_bounds__(256) void gemm_rec1_k(
    const float* __restrict__ z, const float* __restrict__ x,
    const float* __restrict__ u, const float* __restrict__ W,
    const float* __restrict__ bias, float* __restrict__ out)
{
    __shared__ float As[16][36];
    __shared__ float Ws[16][64];
    const int tid = threadIdx.x;
    const int row0 = blockIdx.x * 32;
    const int j0 = blockIdx.y * 64;
    const int tjx = tid & 31;
    const int trg = tid >> 5;
    float acc[4][2];
#pragma unroll
    for (int a = 0; a < 4; a++) { acc[a][0] = 0.f; acc[a][1] = 0.f; }

    for (int kc = 0; kc < 272; kc += 16) {
        __syncthreads();
#pragma unroll
        for (int e = 0; e < 2; e++) {
            int idx = tid + e * 256;
            int r = idx >> 4, kk = idx & 15;
            int k = kc + kk, gr = row0 + r;
            float v;
            if (k < 128)      v = z[gr * 128 + k];
            else if (k < 256) v = x[gr * 128 + (k - 128)];
            else              v = u[gr * 16 + (k - 256)];
            As[kk][r] = v;
        }
        {
            int lin = tid * 4;            // 1024 floats total
            int kk = lin >> 6, jj = lin & 63;
            *(float4*)&Ws[kk][jj] = *(const float4*)(W + (kc + kk) * 128 + j0 + jj);
        }
        __syncthreads();
#pragma unroll
        for (int kk = 0; kk < 16; kk++) {
            const float4 a4 = *(const float4*)&As[kk][trg * 4];
            const float2 w2 = *(const float2*)&Ws[kk][2 * tjx];
            const float av[4] = {a4.x, a4.y, a4.z, a4.w};
#pragma unroll
            for (int rr = 0; rr < 4; rr++) {
                acc[rr][0] += av[rr] * w2.x;
                acc[rr][1] += av[rr] * w2.y;
            }
        }
    }
#pragma unroll
    for (int rr = 0; rr < 4; rr++)
#pragma unroll
        for (int jj = 0; jj < 2; jj++) {
            int r = row0 + trg * 4 + rr;
            int j = j0 + 2 * tjx + jj;
            out[r * 128 + j] = fmaxf(acc[rr][jj] + bias[j], 0.f);
        }
}

// ---------------------------------------------------------------------------
// Mix step: z_next[b,j] = sum_i alpha[b,i] * ([z|u|w][b,:] @ Wmix[:, i*128+j])
// with alpha = softmax([z|u] @ alpha_W) computed in-block.
// Block: 32 rows x (32 j's x 16 i). Grid (64,4). K=272, KC=8.
// ---------------------------------------------------------------------------
__global__ __launch_bounds__(256) void mix_step_k(
    const float* __restrict__ z, const float* __restrict__ u,
    const float* __restrict__ w, const float* __restrict__ aW,
    const float* __restrict__ Wmix, float* __restrict__ zout)
{
    __shared__ float Ak[272][36];     // [k][r]
    __shared__ float Ws[8][512];      // [kk][i*32+jj]
    __shared__ float lg[32][17];
    __shared__ float alph[32][17];
    const int tid = threadIdx.x;
    const int row0 = blockIdx.x * 32;
    const int j0 = blockIdx.y * 32;

    // Stage full A-tile [z|u|w] (32 x 272), k-fast coalesced float4 loads.
#pragma unroll
    for (int e = 0; e < 9; e++) {
        int idx = tid + e * 256;
        if (idx < 2176) {
            int lin = idx * 4;
            int r = lin / 272;
            int k = lin % 272;
            int gr = row0 + r;
            float4 v;
            if (k < 128)      v = *(const float4*)(z + gr * 128 + k);
            else if (k < 144) v = *(const float4*)(u + gr * 16 + (k - 128));
            else              v = *(const float4*)(w + gr * 128 + (k - 144));
            Ak[k + 0][r] = v.x; Ak[k + 1][r] = v.y;
            Ak[k + 2][r] = v.z; Ak[k + 3][r] = v.w;
        }
    }
    __syncthreads();

    // Alpha logits: [z|u] is exactly the first 144 rows of Ak.
#pragma unroll
    for (int e = 0; e < 2; e++) {
        int idx = tid + e * 256;
        int r = idx >> 4, i = idx & 15;
        float s = 0.f;
        for (int k = 0; k < 144; k++) s += Ak[k][r] * aW[k * 16 + i];
        lg[r][i] = s;
    }
    __syncthreads();
    if (tid < 32) {
        float m = -1e30f;
#pragma unroll
        for (int i = 0; i < 16; i++) m = fmaxf(m, lg[tid][i]);
        float ex[16]; float s = 0.f;
#pragma unroll
        for (int i = 0; i < 16; i++) { ex[i] = expf(lg[tid][i] - m); s += ex[i]; }
        float inv = 1.f / s;
#pragma unroll
        for (int i = 0; i < 16; i++) alph[tid][i] = ex[i] * inv;
    }

    const int tjj = tid & 31;
    const int trg = tid >> 5;
    float acc[4][16];
#pragma unroll
    for (int a = 0; a < 4; a++)
#pragma unroll
        for (int i = 0; i < 16; i++) acc[a][i] = 0.f;

    for (int kc = 0; kc < 272; kc += 8) {
        __syncthreads();   // protects Ws (and alph on first iter)
#pragma unroll
        for (int e = 0; e < 4; e++) {
            int idx = tid + e * 256;       // 1024 float4s per chunk
            int lin = idx * 4;
            int kk = lin >> 9, c = lin & 511;
            int i = c >> 5, jj = c & 31;
            *(float4*)&Ws[kk][i * 32 + jj] =
                *(const float4*)(Wmix + (size_t)(kc + kk) * 2048 + i * 128 + j0 + jj);
        }
        __syncthreads();
#pragma unroll
        for (int kk = 0; kk < 8; kk++) {
            const float4 a4 = *(const float4*)&Ak[kc + kk][trg * 4];
            const float av[4] = {a4.x, a4.y, a4.z, a4.w};
#pragma unroll
            for (int i = 0; i < 16; i++) {
                const float wv = Ws[kk][i * 32 + tjj];
                acc[0][i] += av[0] * wv;
                acc[1][i] += av[1] * wv;
                acc[2][i] += av[2] * wv;
                acc[3][i] += av[3] * wv;
            }
        }
    }
#pragma unroll
    for (int rr = 0; rr < 4; rr++) {
        const int r = trg * 4 + rr;
        float s = 0.f;
#pragma unroll
        for (int i = 0; i < 16; i++) s += alph[r][i] * acc[rr][i];
        zout[(row0 + r) * 128 + j0 + tjj] = s;
    }
}

// ---------------------------------------------------------------------------
// Fused 2-layer MLP: out = relu(Z@W1+b1)@W2+b2 for M rows (obs reconstruction).
// Block: 32 rows. Grid M/32.
// ---------------------------------------------------------------------------
__global__ __launch_bounds__(256) void mlp2_k(
    const float* __restrict__ Z, const float* __restrict__ W1,
    const float* __restrict__ b1, const float* __restrict__ W2,
    const float* __restrict__ b2, float* __restrict__ out)
{
    __shared__ float Zs[32][132];
    __shared__ float Hs[32][132];
    __shared__ float Ws[16][128];
    const int tid = threadIdx.x;
    const int row0 = blockIdx.x * 32;
    const int tx = tid & 31;   // j base = 4*tx
    const int ty = tid >> 5;   // row base = 4*ty

    // stage Z (32x128) row-major
#pragma unroll
    for (int e = 0; e < 4; e++) {
        int idx = tid + e * 256;
        int lin = idx * 4;
        int r = lin >> 7, k = lin & 127;
        *(float4*)&Zs[r][k] = *(const float4*)(Z + (size_t)(row0 + r) * 128 + k);
    }

    float acc[4][4];
#pragma unroll
    for (int a = 0; a < 4; a++)
#pragma unroll
        for (int b = 0; b < 4; b++) acc[a][b] = 0.f;

    // layer 1
    for (int kc = 0; kc < 128; kc += 16) {
        __syncthreads();
#pragma unroll
        for (int e = 0; e < 2; e++) {
            int idx = tid + e * 256;
            int lin = idx * 4;
            int kk = lin >> 7, j = lin & 127;
            *(float4*)&Ws[kk][j] = *(const float4*)(W1 + (kc + kk) * 128 + j);
        }
        __syncthreads();
#pragma unroll
        for (int kk = 0; kk < 16; kk++) {
            float av[4];
#pragma unroll
            for (int rr = 0; rr < 4; rr++) av[rr] = Zs[ty * 4 + rr][kc + kk];
            const float4 w4 = *(const float4*)&Ws[kk][tx * 4];
            const float wv[4] = {w4.x, w4.y, w4.z, w4.w};
#pragma unroll
            for (int r = 0; r < 4; r++)
#pragma unroll
                for (int j = 0; j < 4; j++) acc[r][j] += av[r] * wv[j];
        }
    }
    // write hidden (relu) to Hs
#pragma unroll
    for (int rr = 0; rr < 4; rr++) {
        float4 hv;
        hv.x = fmaxf(acc[rr][0] + b1[tx * 4 + 0], 0.f);
        hv.y = fmaxf(acc[rr][1] + b1[tx * 4 + 1], 0.f);
        hv.z = fmaxf(acc[rr][2] + b1[tx * 4 + 2], 0.f);
        hv.w = fmaxf(acc[rr][3] + b1[tx * 4 + 3], 0.f);
        *(float4*)&Hs[ty * 4 + rr][tx * 4] = hv;
    }
#pragma unroll
    for (int a = 0; a < 4; a++)
#pragma unroll
        for (int b = 0; b < 4; b++) acc[a][b] = 0.f;

    // layer 2
    for (int kc = 0; kc < 128; kc += 16) {
        __syncthreads();
#pragma unroll
        for (int e = 0; e < 2; e++) {
            int idx = tid + e * 256;
            int lin = idx * 4;
            int kk = lin >> 7, j = lin & 127;
            *(float4*)&Ws[kk][j] = *(const float4*)(W2 + (kc + kk) * 128 + j);
        }
        __syncthreads();
#pragma unroll
        for (int kk = 0; kk < 16; kk++) {
            float av[4];
#pragma unroll
            for (int rr = 0; rr < 4; rr++) av[rr] = Hs[ty * 4 + rr][kc + kk];
            const float4 w4 = *(const float4*)&Ws[kk][tx * 4];
            const float wv[4] = {w4.x, w4.y, w4.z, w4.w};
#pragma unroll
            for (int r = 0; r < 4; r++)
#pragma unroll
                for (int j = 0; j < 4; j++) acc[r][j] += av[r] * wv[j];
        }
    }
#pragma unroll
    for (int rr = 0; rr < 4; rr++) {
        float4 ov;
        ov.x = acc[rr][0] + b2[tx * 4 + 0];
        ov.y = acc[rr][1] + b2[tx * 4 + 1];
        ov.z = acc[rr][2] + b2[tx * 4 + 2];
        ov.w = acc[rr][3] + b2[tx * 4 + 3];
        *(float4*)(out + (size_t)(row0 + ty * 4 + rr) * 128 + tx * 4) = ov;
    }
}

// ---------------------------------------------------------------------------
extern "C" void kernel_launch(void* const* d_in, const int* in_sizes, int n_in,
                              void* d_out, int out_size, void* d_ws, size_t ws_size,
                              hipStream_t stream)
{
    (void)in_sizes; (void)n_in; (void)out_size; (void)ws_size;
    const float* xs       = (const float*)d_in[0];
    const float* us       = (const float*)d_in[1];
    const float* eps1     = (const float*)d_in[2];
    const float* eps      = (const float*)d_in[3];
    const float* lstm_Wx  = (const float*)d_in[4];
    const float* lstm_Wh  = (const float*)d_in[5];
    const float* lstm_b   = (const float*)d_in[6];
    const float* init_W1  = (const float*)d_in[7];
    const float* init_b1  = (const float*)d_in[8];
    const float* init_W2  = (const float*)d_in[9];
    const float* init_b2  = (const float*)d_in[10];
    const float* trans_W1 = (const float*)d_in[11];
    const float* trans_b1 = (const float*)d_in[12];
    const float* trans_W2 = (const float*)d_in[13];
    const float* trans_b2 = (const float*)d_in[14];
    const float* obs_W1   = (const float*)d_in[15];
    const float* obs_b1   = (const float*)d_in[16];
    const float* obs_W2   = (const float*)d_in[17];
    const float* obs_b2   = (const float*)d_in[18];
    const float* rec_W1   = (const float*)d_in[19];
    const float* rec_b1   = (const float*)d_in[20];
    const float* rec_W2   = (const float*)d_in[21];
    const float* rec_b2   = (const float*)d_in[22];
    const float* alpha_W  = (const float*)d_in[23];
    const float* Amat     = (const float*)d_in[24];
    const float* Bmat     = (const float*)d_in[25];
    const float* Cmat     = (const float*)d_in[26];

    float* out  = (float*)d_out;
    float* zs   = out;                                  // (64*2048, 128)
    float* xrec = out + (size_t)TT * BB * LATN;         // (63*2048, 128)

    float* wsf = (float*)d_ws;
    float* hA   = wsf;                    // 2048*128
    float* hB   = hA + BB * HDN;
    float* cst  = hB + BB * HDN;
    float* hidb = cst + BB * HDN;
    float* w1b  = hidb + BB * HDN;
    float* rb   = w1b + BB * HDN;
    float* wb   = rb + BB * HDN;
    float* wmix = wb + BB * HDN;          // 272*2048

    // Wmix prep
    prep_wmix_k<<<2176, 256, 0, stream>>>(Amat, Bmat, Cmat, wmix);

    // LSTM over T (h double-buffered; even t reads hA writes hB)
    for (int t = 0; t < TT; t++) {
        const float* hin = (t & 1) ? hB : hA;
        float* hout      = (t & 1) ? hA : hB;
        lstm_step_k<<<dim3(64, 4), 256, 0, stream>>>(
            xs + (size_t)t * BB * OBSN, hin, hout, cst,
            lstm_Wx, lstm_Wh, lstm_b, t == 0 ? 1 : 0);
    }
    const float* h_last = hA;  // t=63 (odd) writes hA

    // Initial network tail + initial transition
    gemm_bias_k<1><<<dim3(32, 2), 256, 0, stream>>>(h_last, init_W1, init_b1, hidb, BB, 128, 128);
    gemm_meanvar_k<<<dim3(64, 2), 256, 0, stream>>>(hidb, init_W2, init_b2, eps1, w1b);
    gemm_bias_k<1><<<dim3(32, 2), 256, 0, stream>>>(w1b, trans_W1, trans_b1, rb, BB, 128, 128);
    gemm_bias_k<0><<<dim3(32, 2), 256, 0, stream>>>(rb, trans_W2, trans_b2, zs, BB, 128, 128);

    // Sequential DVBF scan (obs_fn hoisted out — not on critical path)
    for (int t = 0; t < TT - 1; t++) {
        const float* zprev = zs + (size_t)t * BB * LATN;
        float* znext       = zs + (size_t)(t + 1) * BB * LATN;
        const float* ut    = us + (size_t)t * BB * CTRLN;
        gemm_rec1_k<<<dim3(64, 2), 256, 0, stream>>>(
            zprev, xs + (size_t)(t + 1) * BB * OBSN, ut, rec_W1, rec_b1, rb);
        gemm_meanvar_k<<<dim3(64, 2), 256, 0, stream>>>(
            rb, rec_W2, rec_b2, eps + (size_t)t * BB * LATN, wb);
        mix_step_k<<<dim3(64, 4), 256, 0, stream>>>(
            zprev, ut, wb, alpha_W, wmix, znext);
    }

    // x_rec = obs_fn(zs[0..62]) for all rows in parallel
    mlp2_k<<<dim3((TT - 1) * BB / 32), 256, 0, stream>>>(
        zs, obs_W1, obs_b1, obs_W2, obs_b2, xrec);
}

// Round 2
// 1408.857 us; speedup vs baseline: 5.6392x; 5.6392x over previous
//
#include <hip/hip_runtime.h>
#include <math.h>

#define TT   64
#define BB   2048
#define OBSN 128
#define CTRLN 16
#define LATN 128
#define NMN  16
#define HDN  128

typedef __attribute__((ext_vector_type(8))) short short8;
typedef __attribute__((ext_vector_type(4))) float f32x4;

__device__ __forceinline__ float sigf(float x) { return 1.0f / (1.0f + expf(-x)); }

// fp32 -> bf16 bits, round-to-nearest-even
__device__ __forceinline__ unsigned short f2bf(float x) {
    unsigned int u = __float_as_uint(x);
    unsigned int r = (u + 0x7fffu + ((u >> 16) & 1u)) >> 16;
    return (unsigned short)r;
}

__device__ __forceinline__ f32x4 mfma16(short8 a, short8 b, f32x4 c) {
    return __builtin_amdgcn_mfma_f32_16x16x32_bf16(a, b, c, 0, 0, 0);
}

// ---------------------------------------------------------------------------
// Prep: fp32 -> bf16 bulk convert (vec4)
// ---------------------------------------------------------------------------
__global__ __launch_bounds__(256) void cvt_bf4_k(
    const float* __restrict__ in, unsigned short* __restrict__ out, int n4)
{
    int i = blockIdx.x * 256 + threadIdx.x;
    if (i >= n4) return;
    float4 v = ((const float4*)in)[i];
    ushort4 o;
    o.x = f2bf(v.x); o.y = f2bf(v.y); o.z = f2bf(v.z); o.w = f2bf(v.w);
    ((ushort4*)out)[i] = o;
}

// ---------------------------------------------------------------------------
// Prep: pack W (K x N fp32 row-major) into MFMA B-frag order, K zero-padded
// to KT*32.  out[((nt*KT+kt)*64+lane)*8 + j] = W[kt*32+(lane>>4)*8+j][nt*16+(lane&15)]
// ---------------------------------------------------------------------------
__global__ __launch_bounds__(256) void pack_b_k(
    const float* __restrict__ W, unsigned short* __restrict__ out,
    int K, int N, int KT)
{
    int id = blockIdx.x * 256 + threadIdx.x;
    int total = (N / 16) * KT * 64;
    if (id >= total) return;
    int lane = id & 63;
    int kt = (id >> 6) % KT;
    int nt = id / (64 * KT);
    int n = nt * 16 + (lane & 15);
    int kb = kt * 32 + (lane >> 4) * 8;
#pragma unroll
    for (int j = 0; j < 8; j++) {
        int k = kb + j;
        out[(size_t)id * 8 + j] = (k < K) ? f2bf(W[(size_t)k * N + n]) : (unsigned short)0;
    }
}

// Pack [Wx;Wh] (K=256, N=512, KT=8)
__global__ __launch_bounds__(256) void pack_lstm_k(
    const float* __restrict__ Wx, const float* __restrict__ Wh,
    unsigned short* __restrict__ out)
{
    int id = blockIdx.x * 256 + threadIdx.x;
    if (id >= 32 * 8 * 64) return;
    int lane = id & 63;
    int kt = (id >> 6) & 7;
    int nt = id >> 9;
    int n = nt * 16 + (lane & 15);
    int kb = kt * 32 + (lane >> 4) * 8;
#pragma unroll
    for (int j = 0; j < 8; j++) {
        int k = kb + j;
        float v = (k < 128) ? Wx[(size_t)k * 512 + n] : Wh[(size_t)(k - 128) * 512 + n];
        out[(size_t)id * 8 + j] = f2bf(v);
    }
}

// Pack Wmix: k-rows [A(z):0-127 | Bm(u):128-143 | C(w):144-271 | 0:272-287],
// col c = i*128+j. K=272->KT=9, N=2048.
__global__ __launch_bounds__(256) void pack_wmix_k(
    const float* __restrict__ A, const float* __restrict__ Bm,
    const float* __restrict__ C, unsigned short* __restrict__ out)
{
    int id = blockIdx.x * 256 + threadIdx.x;
    if (id >= 128 * 9 * 64) return;
    int lane = id & 63;
    int kt = (id >> 6) % 9;
    int nt = id / (64 * 9);
    int c = nt * 16 + (lane & 15);
    int i = c >> 7, jj = c & 127;
    int kb = kt * 32 + (lane >> 4) * 8;
#pragma unroll
    for (int j = 0; j < 8; j++) {
        int k = kb + j;
        float v;
        if (k < 128)      v = A[((size_t)(i * 128 + jj)) * 128 + k];
        else if (k < 144) v = Bm[(size_t)(i * 128 + jj) * 16 + (k - 128)];
        else if (k < 272) v = C[(size_t)(i * 128 + jj) * 128 + (k - 144)];
        else              v = 0.f;
        out[(size_t)id * 8 + j] = f2bf(v);
    }
}

// ---------------------------------------------------------------------------
// Persistent LSTM: 128 blocks x 512 threads, 16 batch rows per block,
// 64 time steps in-block. h (bf16) and c (fp32) live in LDS.
// ---------------------------------------------------------------------------
__global__ __launch_bounds__(512) void lstm_k(
    const unsigned short* __restrict__ xs_bf,   // (64,2048,128)
    const unsigned short* __restrict__ lstm_pk, // nt32 x kt8 frag-packed
    const float* __restrict__ bias,             // 512
    float* __restrict__ hlast)                  // (2048,128)
{
    __shared__ unsigned short h_bf[16][136];
    __shared__ float cs[16][128];
    __shared__ float gb[16][516];
    __shared__ float bs[512];

    const int tid = threadIdx.x;
    const int lane = tid & 63;
    const int w = tid >> 6;          // wave 0..7
    const int quad = lane >> 4;
    const int l15 = lane & 15;
    const int row0 = blockIdx.x * 16;

    bs[tid] = bias[tid];
    for (int idx = tid; idx < 16 * 136; idx += 512) h_bf[idx / 136][idx % 136] = 0;
    for (int idx = tid; idx < 2048; idx += 512) cs[idx >> 7][idx & 127] = 0.f;
    __syncthreads();

    for (int t = 0; t < TT; t++) {
        short8 a[8];
#pragma unroll
        for (int kt = 0; kt < 4; kt++)
            a[kt] = *(const short8*)&xs_bf[((size_t)t * 2048 + row0 + l15) * 128 + kt * 32 + quad * 8];
#pragma unroll
        for (int kt = 4; kt < 8; kt++)
            a[kt] = *(const short8*)&h_bf[l15][(kt - 4) * 32 + quad * 8];

        f32x4 D[4];
#pragma unroll
        for (int s = 0; s < 4; s++) D[s] = (f32x4){0.f, 0.f, 0.f, 0.f};
#pragma unroll
        for (int kt = 0; kt < 8; kt++) {
#pragma unroll
            for (int s = 0; s < 4; s++) {
                int ntg = w * 4 + s;
                short8 b = *(const short8*)&lstm_pk[(((size_t)ntg * 8 + kt) * 64 + lane) * 8];
                D[s] = mfma16(a[kt], b, D[s]);
            }
        }
#pragma unroll
        for (int s = 0; s < 4; s++)
#pragma unroll
            for (int rg = 0; rg < 4; rg++)
                gb[quad * 4 + rg][(w * 4 + s) * 16 + l15] = D[s][rg];
        __syncthreads();

#pragma unroll
        for (int e = 0; e < 4; e++) {
            int idx = tid + e * 512;
            int r = idx >> 7, j = idx & 127;
            float gi = gb[r][j] + bs[j];
            float gf = gb[r][128 + j] + bs[128 + j];
            float gg = gb[r][256 + j] + bs[256 + j];
            float go = gb[r][384 + j] + bs[384 + j];
            float c = sigf(gf) * cs[r][j] + sigf(gi) * tanhf(gg);
            float h = sigf(go) * tanhf(c);
            cs[r][j] = c;
            h_bf[r][j] = f2bf(h);
            if (t == TT - 1) hlast[(size_t)(row0 + r) * 128 + j] = h;
        }
        __syncthreads();
    }
}

// ---------------------------------------------------------------------------
// Persistent DVBF scan: 128 blocks x 512 threads, 16 rows, 63 steps in-block.
// amix LDS layout per row: [z:0-127 | u:128-143 | w:144-271 | 0:272-287]
// ---------------------------------------------------------------------------
__global__ __launch_bounds__(512) void scan_k(
    const unsigned short* __restrict__ xs_bf,
    const unsigned short* __restrict__ us_bf,
    const float* __restrict__ eps,
    const unsigned short* __restrict__ rec1_pk,  // nt8 kt9
    const float* __restrict__ rec_b1,
    const unsigned short* __restrict__ rec2_pk,  // nt16 kt4
    const float* __restrict__ rec_b2,
    const unsigned short* __restrict__ alpha_pk, // nt1 kt5
    const unsigned short* __restrict__ wmix_pk,  // nt128 kt9
    float* __restrict__ zs)
{
    __shared__ unsigned short amix[16][296];
    __shared__ unsigned short rb_bf[16][136];
    __shared__ float wv[16][260];
    __shared__ float part[8][16][132];
    __shared__ float logits[16][20];
    __shared__ float alph[16][20];
    __shared__ float b1s[128];
    __shared__ float b2s[256];

    const int tid = threadIdx.x;
    const int lane = tid & 63;
    const int w = tid >> 6;
    const int quad = lane >> 4;
    const int l15 = lane & 15;
    const int row0 = blockIdx.x * 16;

    if (tid < 128) b1s[tid] = rec_b1[tid];
    if (tid < 256) b2s[tid] = rec_b2[tid];
    for (int idx = tid; idx < 256; idx += 512)
        amix[idx >> 4][272 + (idx & 15)] = 0;
    for (int idx = tid; idx < 2048; idx += 512) {
        int r = idx >> 7, j = idx & 127;
        amix[r][j] = f2bf(zs[(size_t)(row0 + r) * 128 + j]);
    }
    __syncthreads();

    for (int t = 0; t < TT - 1; t++) {
        // phase a: stage u_t into amix
        if (tid < 256) {
            int r = tid >> 4, c = tid & 15;
            amix[r][128 + c] = us_bf[((size_t)t * 2048 + row0 + r) * 16 + c];
        }
        __syncthreads();

        // phase b: rec1  r = relu([z|x_{t+1}|u] @ W1 + b1); wave w -> n-tile w
        {
            short8 a[9];
#pragma unroll
            for (int kt = 0; kt < 4; kt++)
                a[kt] = *(const short8*)&amix[l15][kt * 32 + quad * 8];
#pragma unroll
            for (int kt = 4; kt < 8; kt++)
                a[kt] = *(const short8*)&xs_bf[((size_t)(t + 1) * 2048 + row0 + l15) * 128 + (kt - 4) * 32 + quad * 8];
            {
                short8 zz = {0, 0, 0, 0, 0, 0, 0, 0};
                a[8] = (quad < 2) ? *(const short8*)&amix[l15][128 + quad * 8] : zz;
            }
            f32x4 D = {0.f, 0.f, 0.f, 0.f};
#pragma unroll
            for (int kt = 0; kt < 9; kt++) {
                short8 b = *(const short8*)&rec1_pk[(((size_t)w * 9 + kt) * 64 + lane) * 8];
                D = mfma16(a[kt], b, D);
            }
            int col = w * 16 + l15;
#pragma unroll
            for (int rg = 0; rg < 4; rg++) {
                float v = fmaxf(D[rg] + b1s[col], 0.f);
                rb_bf[quad * 4 + rg][col] = f2bf(v);
            }
        }
        __syncthreads();

        // phase c: rec2 (mean|logvar, 16 n-tiles, 2 per wave) + alpha logits on wave 7
        {
            short8 a[4];
#pragma unroll
            for (int kt = 0; kt < 4; kt++)
                a[kt] = *(const short8*)&rb_bf[l15][kt * 32 + quad * 8];
            f32x4 D0 = {0.f, 0.f, 0.f, 0.f}, D1 = {0.f, 0.f, 0.f, 0.f};
            const int nt0 = w * 2, nt1 = w * 2 + 1;
#pragma unroll
            for (int kt = 0; kt < 4; kt++) {
                short8 b0 = *(const short8*)&rec2_pk[(((size_t)nt0 * 4 + kt) * 64 + lane) * 8];
                short8 b1 = *(const short8*)&rec2_pk[(((size_t)nt1 * 4 + kt) * 64 + lane) * 8];
                D0 = mfma16(a[kt], b0, D0);
                D1 = mfma16(a[kt], b1, D1);
            }
#pragma unroll
            for (int rg = 0; rg < 4; rg++) {
                wv[quad * 4 + rg][nt0 * 16 + l15] = D0[rg];
                wv[quad * 4 + rg][nt1 * 16 + l15] = D1[rg];
            }
            if (w == 7) {
                short8 az[5];
#pragma unroll
                for (int kt = 0; kt < 4; kt++)
                    az[kt] = *(const short8*)&amix[l15][kt * 32 + quad * 8];
                short8 zz = {0, 0, 0, 0, 0, 0, 0, 0};
                az[4] = (quad < 2) ? *(const short8*)&amix[l15][128 + quad * 8] : zz;
                f32x4 DL = {0.f, 0.f, 0.f, 0.f};
#pragma unroll
                for (int kt = 0; kt < 5; kt++) {
                    short8 b = *(const short8*)&alpha_pk[((size_t)kt * 64 + lane) * 8];
                    DL = mfma16(az[kt], b, DL);
                }
#pragma unroll
                for (int rg = 0; rg < 4; rg++)
                    logits[quad * 4 + rg][l15] = DL[rg];
            }
        }
        __syncthreads();

        // phase d: softmax (16 threads) + w = mean + exp(lv/2)*eps into amix
        if (tid < 16) {
            float m = -1e30f;
#pragma unroll
            for (int i = 0; i < 16; i++) m = fmaxf(m, logits[tid][i]);
            float ex[16];
            float s = 0.f;
#pragma unroll
            for (int i = 0; i < 16; i++) { ex[i] = expf(logits[tid][i] - m); s += ex[i]; }
            float inv = 1.f / s;
#pragma unroll
            for (int i = 0; i < 16; i++) alph[tid][i] = ex[i] * inv;
        }
#pragma unroll
        for (int e = 0; e < 4; e++) {
            int idx = tid + e * 512;
            int r = idx >> 7, j = idx & 127;
            float mv = wv[r][j] + b2s[j];
            float lv = wv[r][128 + j] + b2s[128 + j];
            float wval = mv + expf(0.5f * lv) * eps[((size_t)t * 2048 + row0 + r) * 128 + j];
            amix[r][144 + j] = f2bf(wval);
        }
        __syncthreads();

        // phase e: mix GEMM. wave w handles i0=2w, i1=2w+1; 8 j-tiles each.
        {
            short8 a[9];
#pragma unroll
            for (int kt = 0; kt < 9; kt++)
                a[kt] = *(const short8*)&amix[l15][kt * 32 + quad * 8];
            const int i0 = 2 * w, i1 = 2 * w + 1;
            float a0[4], a1[4];
#pragma unroll
            for (int rg = 0; rg < 4; rg++) {
                a0[rg] = alph[quad * 4 + rg][i0];
                a1[rg] = alph[quad * 4 + rg][i1];
            }
#pragma unroll 1
            for (int jt = 0; jt < 8; jt++) {
                f32x4 D0 = {0.f, 0.f, 0.f, 0.f}, D1 = {0.f, 0.f, 0.f, 0.f};
#pragma unroll
                for (int kt = 0; kt < 9; kt++) {
                    short8 b0 = *(const short8*)&wmix_pk[((((size_t)i0 * 8 + jt) * 9 + kt) * 64 + lane) * 8];
                    short8 b1 = *(const short8*)&wmix_pk[((((size_t)i1 * 8 + jt) * 9 + kt) * 64 + lane) * 8];
                    D0 = mfma16(a[kt], b0, D0);
                    D1 = mfma16(a[kt], b1, D1);
                }
#pragma unroll
                for (int rg = 0; rg < 4; rg++)
                    part[w][quad * 4 + rg][jt * 16 + l15] = a0[rg] * D0[rg] + a1[rg] * D1[rg];
            }
        }
        __syncthreads();

        // phase f: reduce 8 partials -> z_{t+1}; write out + feed back (bf16)
#pragma unroll
        for (int e = 0; e < 4; e++) {
            int idx = tid + e * 512;
            int r = idx >> 7, j = idx & 127;
            float s = 0.f;
#pragma unroll
            for (int ww = 0; ww < 8; ww++) s += part[ww][r][j];
            zs[((size_t)(t + 1) * 2048 + row0 + r) * 128 + j] = s;
            amix[r][j] = f2bf(s);
        }
        __syncthreads();
    }
}

// ---------------------------------------------------------------------------
// fp32 helper GEMMs for the small init-network tail (unchanged from R1)
// ---------------------------------------------------------------------------
template <int RELU>
__global__ __launch_bounds__(256) void gemm_bias_k(
    const float* __restrict__ A, const float* __restrict__ W,
    const float* __restrict__ bias, float* __restrict__ Cout,
    int M, int K, int N)
{
    __shared__ float As[16][68];
    __shared__ float Ws[16][64];
    const int tid = threadIdx.x;
    const int row0 = blockIdx.x * 64;
    const int col0 = blockIdx.y * 64;
    const int tx = tid & 15, ty = tid >> 4;
    float acc[4][4];
#pragma unroll
    for (int a = 0; a < 4; a++)
#pragma unroll
        for (int b = 0; b < 4; b++) acc[a][b] = 0.f;

    for (int kc = 0; kc < K; kc += 16) {
        __syncthreads();
#pragma unroll
        for (int e = 0; e < 4; e++) {
            int idx = tid + e * 256;
            int r = idx >> 4, kk = idx & 15;
            As[kk][r] = A[(size_t)(row0 + r) * K + kc + kk];
        }
#pragma unroll
        for (int e = 0; e < 4; e++) {
            int idx = tid + e * 256;
            int kk = idx >> 6, jj = idx & 63;
            Ws[kk][jj] = W[(kc + kk) * N + col0 + jj];
        }
        __syncthreads();
#pragma unroll
        for (int kk = 0; kk < 16; kk++) {
            const float4 a4 = *(const float4*)&As[kk][ty * 4];
            const float4 w4 = *(const float4*)&Ws[kk][tx * 4];
            const float av[4] = {a4.x, a4.y, a4.z, a4.w};
            const float wv2[4] = {w4.x, w4.y, w4.z, w4.w};
#pragma unroll
            for (int r = 0; r < 4; r++)
#pragma unroll
                for (int j = 0; j < 4; j++) acc[r][j] += av[r] * wv2[j];
        }
    }
#pragma unroll
    for (int r = 0; r < 4; r++)
#pragma unroll
        for (int j = 0; j < 4; j++) {
            int gr = row0 + ty * 4 + r, gc = col0 + tx * 4 + j;
            float v = acc[r][j] + bias[gc];
            if (RELU) v = fmaxf(v, 0.f);
            Cout[(size_t)gr * N + gc] = v;
        }
}

__global__ __launch_bounds__(256) void gemm_meanvar_k(
    const float* __restrict__ A, const float* __restrict__ W,
    const float* __restrict__ bias, const float* __restrict__ eps,
    float* __restrict__ out)
{
    __shared__ float As[16][36];
    __shared__ float Ws[16][128];
    const int tid = threadIdx.x;
    const int row0 = blockIdx.x * 32;
    const int j0 = blockIdx.y * 64;
    const int tjx = tid & 31;
    const int trg = tid >> 5;
    float am[4][2], al[4][2];
#pragma unroll
    for (int a = 0; a < 4; a++) { am[a][0] = am[a][1] = 0.f; al[a][0] = al[a][1] = 0.f; }

    for (int kc = 0; kc < 128; kc += 16) {
        __syncthreads();
#pragma unroll
        for (int e = 0; e < 2; e++) {
            int idx = tid + e * 256;
            int r = idx >> 4, kk = idx & 15;
            As[kk][r] = A[(row0 + r) * 128 + kc + kk];
        }
#pragma unroll
        for (int e = 0; e < 2; e++) {
            int idx = tid + e * 256;
            int lin = idx * 4;
            int kk = lin >> 7, cc = lin & 127;
            int half = cc >> 6, jj = cc & 63;
            *(float4*)&Ws[kk][half * 64 + jj] =
                *(const float4*)(W + (kc + kk) * 256 + half * 128 + j0 + jj);
        }
        __syncthreads();
#pragma unroll
        for (int kk = 0; kk < 16; kk++) {
            const float4 a4 = *(const float4*)&As[kk][trg * 4];
            const float2 wm = *(const float2*)&Ws[kk][2 * tjx];
            const float2 wl = *(const float2*)&Ws[kk][64 + 2 * tjx];
            const float av[4] = {a4.x, a4.y, a4.z, a4.w};
#pragma unroll
            for (int rr = 0; rr < 4; rr++) {
                am[rr][0] += av[rr] * wm.x; am[rr][1] += av[rr] * wm.y;
                al[rr][0] += av[rr] * wl.x; al[rr][1] += av[rr] * wl.y;
            }
        }
    }
#pragma unroll
    for (int rr = 0; rr < 4; rr++)
#pragma unroll
        for (int jj = 0; jj < 2; jj++) {
            int r = row0 + trg * 4 + rr;
            int j = j0 + 2 * tjx + jj;
            float m = am[rr][jj] + bias[j];
            float l = al[rr][jj] + bias[128 + j];
            out[r * 128 + j] = m + expf(0.5f * l) * eps[r * 128 + j];
        }
}

// ---------------------------------------------------------------------------
// Fused 2-layer MLP for x_rec (fp32, unchanged from R1)
// ---------------------------------------------------------------------------
__global__ __launch_bounds__(256) void mlp2_k(
    const float* __restrict__ Z, const float* __restrict__ W1,
    const float* __restrict__ b1, const float* __restrict__ W2,
    const float* __restrict__ b2, float* __restrict__ out)
{
    __shared__ float Zs[32][132];
    __shared__ float Hs[32][132];
    __shared__ float Ws[16][128];
    const int tid = threadIdx.x;
    const int row0 = blockIdx.x * 32;
    const int tx = tid & 31;
    const int ty = tid >> 5;

#pragma unroll
    for (int e = 0; e < 4; e++) {
        int idx = tid + e * 256;
        int lin = idx * 4;
        int r = lin >> 7, k = lin & 127;
        *(float4*)&Zs[r][k] = *(const float4*)(Z + (size_t)(row0 + r) * 128 + k);
    }

    float acc[4][4];
#pragma unroll
    for (int a = 0; a < 4; a++)
#pragma unroll
        for (int b = 0; b < 4; b++) acc[a][b] = 0.f;

    for (int kc = 0; kc < 128; kc += 16) {
        __syncthreads();
#pragma unroll
        for (int e = 0; e < 2; e++) {
            int idx = tid + e * 256;
            int lin = idx * 4;
            int kk = lin >> 7, j = lin & 127;
            *(float4*)&Ws[kk][j] = *(const float4*)(W1 + (kc + kk) * 128 + j);
        }
        __syncthreads();
#pragma unroll
        for (int kk = 0; kk < 16; kk++) {
            float av[4];
#pragma unroll
            for (int rr = 0; rr < 4; rr++) av[rr] = Zs[ty * 4 + rr][kc + kk];
            const float4 w4 = *(const float4*)&Ws[kk][tx * 4];
            const float wv2[4] = {w4.x, w4.y, w4.z, w4.w};
#pragma unroll
            for (int r = 0; r < 4; r++)
#pragma unroll
                for (int j = 0; j < 4; j++) acc[r][j] += av[r] * wv2[j];
        }
    }
#pragma unroll
    for (int rr = 0; rr < 4; rr++) {
        float4 hv;
        hv.x = fmaxf(acc[rr][0] + b1[tx * 4 + 0], 0.f);
        hv.y = fmaxf(acc[rr][1] + b1[tx * 4 + 1], 0.f);
        hv.z = fmaxf(acc[rr][2] + b1[tx * 4 + 2], 0.f);
        hv.w = fmaxf(acc[rr][3] + b1[tx * 4 + 3], 0.f);
        *(float4*)&Hs[ty * 4 + rr][tx * 4] = hv;
    }
#pragma unroll
    for (int a = 0; a < 4; a++)
#pragma unroll
        for (int b = 0; b < 4; b++) acc[a][b] = 0.f;

    for (int kc = 0; kc < 128; kc += 16) {
        __syncthreads();
#pragma unroll
        for (int e = 0; e < 2; e++) {
            int idx = tid + e * 256;
            int lin = idx * 4;
            int kk = lin >> 7, j = lin & 127;
            *(float4*)&Ws[kk][j] = *(const float4*)(W2 + (kc + kk) * 128 + j);
        }
        __syncthreads();
#pragma unroll
        for (int kk = 0; kk < 16; kk++) {
            float av[4];
#pragma unroll
            for (int rr = 0; rr < 4; rr++) av[rr] = Hs[ty * 4 + rr][kc + kk];
            const float4 w4 = *(const float4*)&Ws[kk][tx * 4];
            const float wv2[4] = {w4.x, w4.y, w4.z, w4.w};
#pragma unroll
            for (int r = 0; r < 4; r++)
#pragma unroll
                for (int j = 0; j < 4; j++) acc[r][j] += av[r] * wv2[j];
        }
    }
#pragma unroll
    for (int rr = 0; rr < 4; rr++) {
        float4 ov;
        ov.x = acc[rr][0] + b2[tx * 4 + 0];
        ov.y = acc[rr][1] + b2[tx * 4 + 1];
        ov.z = acc[rr][2] + b2[tx * 4 + 2];
        ov.w = acc[rr][3] + b2[tx * 4 + 3];
        *(float4*)(out + (size_t)(row0 + ty * 4 + rr) * 128 + tx * 4) = ov;
    }
}

// ---------------------------------------------------------------------------
extern "C" void kernel_launch(void* const* d_in, const int* in_sizes, int n_in,
                              void* d_out, int out_size, void* d_ws, size_t ws_size,
                              hipStream_t stream)
{
    (void)in_sizes; (void)n_in; (void)out_size; (void)ws_size;
    const float* xs       = (const float*)d_in[0];
    const float* us       = (const float*)d_in[1];
    const float* eps1     = (const float*)d_in[2];
    const float* eps      = (const float*)d_in[3];
    const float* lstm_Wx  = (const float*)d_in[4];
    const float* lstm_Wh  = (const float*)d_in[5];
    const float* lstm_b   = (const float*)d_in[6];
    const float* init_W1  = (const float*)d_in[7];
    const float* init_b1  = (const float*)d_in[8];
    const float* init_W2  = (const float*)d_in[9];
    const float* init_b2  = (const float*)d_in[10];
    const float* trans_W1 = (const float*)d_in[11];
    const float* trans_b1 = (const float*)d_in[12];
    const float* trans_W2 = (const float*)d_in[13];
    const float* trans_b2 = (const float*)d_in[14];
    const float* obs_W1   = (const float*)d_in[15];
    const float* obs_b1   = (const float*)d_in[16];
    const float* obs_W2   = (const float*)d_in[17];
    const float* obs_b2   = (const float*)d_in[18];
    const float* rec_W1   = (const float*)d_in[19];
    const float* rec_b1   = (const float*)d_in[20];
    const float* rec_W2   = (const float*)d_in[21];
    const float* rec_b2   = (const float*)d_in[22];
    const float* alpha_W  = (const float*)d_in[23];
    const float* Amat     = (const float*)d_in[24];
    const float* Bmat     = (const float*)d_in[25];
    const float* Cmat     = (const float*)d_in[26];

    float* out  = (float*)d_out;
    float* zs   = out;                           // (64*2048, 128)
    float* xrec = out + (size_t)TT * BB * LATN;  // (63*2048, 128)

    // workspace layout (bytes)
    char* ws = (char*)d_ws;
    unsigned short* xs_bf   = (unsigned short*)(ws);                    // 33,554,432 B
    unsigned short* us_bf   = (unsigned short*)(ws + 33554432);         //  4,194,304 B
    unsigned short* lstm_pk = (unsigned short*)(ws + 37748736);         //    262,144 B
    unsigned short* rec1_pk = (unsigned short*)(ws + 38010880);         //     73,728 B
    unsigned short* rec2_pk = (unsigned short*)(ws + 38084608);         //     65,536 B
    unsigned short* alpha_pk= (unsigned short*)(ws + 38150144);         //      5,120 B
    unsigned short* wmix_pk = (unsigned short*)(ws + 38155264);         //  1,179,648 B
    float* hlast            = (float*)(ws + 39334912);                  //  1,048,576 B
    float* hidb             = (float*)(ws + 40383488);
    float* w1b              = (float*)(ws + 41432064);
    float* rbg              = (float*)(ws + 42480640);                  // ends 43,529,216

    // ---- prep ----
    cvt_bf4_k<<<16384, 256, 0, stream>>>(xs, xs_bf, 4194304);
    cvt_bf4_k<<<2048, 256, 0, stream>>>(us, us_bf, 524288);
    pack_lstm_k<<<64, 256, 0, stream>>>(lstm_Wx, lstm_Wh, lstm_pk);
    pack_b_k<<<18, 256, 0, stream>>>(rec_W1, rec1_pk, 272, 128, 9);
    pack_b_k<<<16, 256, 0, stream>>>(rec_W2, rec2_pk, 128, 256, 4);
    pack_b_k<<<2, 256, 0, stream>>>(alpha_W, alpha_pk, 144, 16, 5);
    pack_wmix_k<<<288, 256, 0, stream>>>(Amat, Bmat, Cmat, wmix_pk);

    // ---- LSTM (persistent) ----
    lstm_k<<<128, 512, 0, stream>>>(xs_bf, lstm_pk, lstm_b, hlast);

    // ---- init-network tail + initial transition (fp32) ----
    gemm_bias_k<1><<<dim3(32, 2), 256, 0, stream>>>(hlast, init_W1, init_b1, hidb, BB, 128, 128);
    gemm_meanvar_k<<<dim3(64, 2), 256, 0, stream>>>(hidb, init_W2, init_b2, eps1, w1b);
    gemm_bias_k<1><<<dim3(32, 2), 256, 0, stream>>>(w1b, trans_W1, trans_b1, rbg, BB, 128, 128);
    gemm_bias_k<0><<<dim3(32, 2), 256, 0, stream>>>(rbg, trans_W2, trans_b2, zs, BB, 128, 128);

    // ---- DVBF scan (persistent) ----
    scan_k<<<128, 512, 0, stream>>>(xs_bf, us_bf, eps,
                                    rec1_pk, rec_b1, rec2_pk, rec_b2,
                                    alpha_pk, wmix_pk, zs);

    // ---- x_rec = obs_fn(zs[0..62]) ----
    mlp2_k<<<dim3((TT - 1) * BB / 32), 256, 0, stream>>>(
        zs, obs_W1, obs_b1, obs_W2, obs_b2, xrec);
}